// Round 5
// baseline (2004.804 us; speedup 1.0000x reference)
//
#include <hip/hip_runtime.h>
#include <hip/hip_bf16.h>

typedef unsigned short u16;
typedef _Float16 f16;
typedef f16 f16x8 __attribute__((ext_vector_type(8)));
typedef f16 half2t __attribute__((ext_vector_type(2)));
typedef u16 u16x8 __attribute__((ext_vector_type(8)));
typedef float f32x4 __attribute__((ext_vector_type(4)));

#define NN 50000
#define NE 800000
#define D  300
#define DP 320   // padded feature dim
#define HP 640   // padded hidden dim
#define MT 64    // rows per k_mlp block
#define NROWPAD 50048

__device__ __forceinline__ float h2f(u16 u){ f16 h = __builtin_bit_cast(f16, u); return (float)h; }
__device__ __forceinline__ u16 f2h(float f){ f16 h = (f16)f; return __builtin_bit_cast(u16, h); }
__device__ __forceinline__ float hlo(unsigned u){ half2t h = __builtin_bit_cast(half2t, u); return (float)h.x; }
__device__ __forceinline__ float hhi(unsigned u){ half2t h = __builtin_bit_cast(half2t, u); return (float)h.y; }
__device__ __forceinline__ unsigned packh(float x, float y){ half2t h; h.x = (f16)x; h.y = (f16)y; return __builtin_bit_cast(unsigned, h); }

__device__ __forceinline__ f32x4 mfma_f16(u16x8 a, u16x8 b, f32x4 c){
  return __builtin_amdgcn_mfma_f32_16x16x32_f16(__builtin_bit_cast(f16x8, a),
                                                __builtin_bit_cast(f16x8, b), c, 0, 0, 0);
}

// ---------------- CSR build (by dst) + per-(dst,combo) counts ----------------
__global__ void k_count(const int* __restrict__ ei, const int* __restrict__ ea,
                        int* __restrict__ cnt, int* __restrict__ ccnt){
  int e = blockIdx.x * 256 + threadIdx.x;
  if (e < NE){
    int d = ei[NE + e];
    atomicAdd(&cnt[d], 1);
    int t = ea[2*e] * 3 + ea[2*e + 1];     // attrs in [0,3)
    atomicAdd(&ccnt[d * 12 + t], 1);
  }
}

__global__ void k_scan1(const int* __restrict__ cnt, int* __restrict__ rp, int* __restrict__ bsum){
  __shared__ int s[1024];
  int i = blockIdx.x * 1024 + threadIdx.x;
  int v = (i < NN) ? cnt[i] : 0;
  s[threadIdx.x] = v;
  __syncthreads();
  for (int off = 1; off < 1024; off <<= 1){
    int t = (threadIdx.x >= off) ? s[threadIdx.x - off] : 0;
    __syncthreads();
    s[threadIdx.x] += t;
    __syncthreads();
  }
  if (i < NN) rp[i] = s[threadIdx.x] - v;
  if (threadIdx.x == 1023) bsum[blockIdx.x] = s[1023];
}

__global__ void k_scan2(int* __restrict__ bsum, int nb){
  __shared__ int s[64];
  int v = (threadIdx.x < nb) ? bsum[threadIdx.x] : 0;
  s[threadIdx.x] = v; __syncthreads();
  for (int off = 1; off < 64; off <<= 1){
    int t = (threadIdx.x >= off) ? s[threadIdx.x - off] : 0;
    __syncthreads();
    s[threadIdx.x] += t;
    __syncthreads();
  }
  if (threadIdx.x < nb) bsum[threadIdx.x] = s[threadIdx.x] - v;
}

__global__ void k_scan3(int* __restrict__ rp, int* __restrict__ cur, const int* __restrict__ bsum){
  int i = blockIdx.x * 256 + threadIdx.x;
  if (i < NN){ int v = rp[i] + bsum[i >> 10]; rp[i] = v; cur[i] = v; }
  if (i == 0) rp[NN] = NE;
}

__global__ void k_fill(const int* __restrict__ ei, int* __restrict__ cur, int* __restrict__ pack){
  int e = blockIdx.x * 256 + threadIdx.x;
  if (e >= NE) return;
  int d = ei[NE + e];
  int pos = atomicAdd(&cur[d], 1);
  pack[pos] = ei[e];                       // src only
}

// ---------------- weight transpose + pad -> fp16 ----------------
__global__ void k_wconv(const float* __restrict__ W1, const float* __restrict__ W2,
                        u16* __restrict__ W1t, u16* __restrict__ W2t){
  int i = blockIdx.x * 256 + threadIdx.x;
  {
    int l = i / (HP * DP); int rem = i % (HP * DP); int n = rem / DP, k = rem % DP;
    float v = (n < 600 && k < D) ? W1[((size_t)l * D + k) * 600 + n] : 0.f;
    W1t[i] = f2h(v);
  }
  {
    int l = i / (DP * HP); int rem = i % (DP * HP); int n = rem / HP, k = rem % HP;
    float v = (n < D && k < 600) ? W2[((size_t)l * 600 + k) * D + n] : 0.f;
    W2t[i] = f2h(v);
  }
}

// ---------------- node embedding -> fp16 padded ----------------
__global__ void k_nodeemb(const int* __restrict__ x, const float* __restrict__ xemb, u16* __restrict__ hb){
  int v = blockIdx.x, c = threadIdx.x;  // block = DP threads
  float y = 0.f;
  if (c < D){
    int a = x[2*v], b = x[2*v + 1];
    y = xemb[(size_t)a * D + c] + xemb[(size_t)b * D + c];
  }
  hb[(size_t)v * DP + c] = f2h(y);
}

// ---------------- per-layer aggregation: one wave per node ----------------
__global__ __launch_bounds__(256) void k_agg(const u16* __restrict__ hb, const int* __restrict__ rp,
    const int* __restrict__ pack, const int* __restrict__ ccnt,
    const float* __restrict__ eemb, u16* __restrict__ agg){
  __shared__ float se[4 * DP];   // rows e0,e1,e2,e4 (fp32)
  for (int i = threadIdx.x; i < 4 * DP; i += 256){
    int t = i / DP, c = i % DP;
    int row = (t == 3) ? 4 : t;
    se[i] = (c < D) ? eemb[row * D + c] : 0.f;
  }
  __syncthreads();
  const int wid = threadIdx.x >> 6, lane = threadIdx.x & 63;
  const int v = blockIdx.x * 4 + wid;
  if (v >= NN) return;
  const char* __restrict__ hbb = (const char*)hb;
  const unsigned lo8 = (unsigned)lane * 8u;          // cols 4l..4l+3
  const unsigned lo4 = 512u + (unsigned)lane * 4u;   // cols 256+2l (lanes<32)
  float a0, a1, a2, a3, a4 = 0.f, a5 = 0.f;
  {
    unsigned off = (unsigned)v * 640u;
    uint2 u = *(const uint2*)(hbb + off + lo8);
    a0 = hlo(u.x); a1 = hhi(u.x); a2 = hlo(u.y); a3 = hhi(u.y);
    if (lane < 32){ unsigned uw = *(const unsigned*)(hbb + off + lo4); a4 = hlo(uw); a5 = hhi(uw); }
  }
  int p = rp[v];
  const int pe = rp[v + 1];
  for (; p + 2 <= pe; p += 2){
    unsigned off0 = (unsigned)pack[p] * 640u;
    unsigned off1 = (unsigned)pack[p + 1] * 640u;
    uint2 u0 = *(const uint2*)(hbb + off0 + lo8);
    uint2 u1 = *(const uint2*)(hbb + off1 + lo8);
    unsigned w0v = 0, w1v = 0;
    if (lane < 32){
      w0v = *(const unsigned*)(hbb + off0 + lo4);
      w1v = *(const unsigned*)(hbb + off1 + lo4);
    }
    a0 += hlo(u0.x) + hlo(u1.x);
    a1 += hhi(u0.x) + hhi(u1.x);
    a2 += hlo(u0.y) + hlo(u1.y);
    a3 += hhi(u0.y) + hhi(u1.y);
    a4 += hlo(w0v) + hlo(w1v);
    a5 += hhi(w0v) + hhi(w1v);
  }
  if (p < pe){
    unsigned off0 = (unsigned)pack[p] * 640u;
    uint2 u0 = *(const uint2*)(hbb + off0 + lo8);
    a0 += hlo(u0.x); a1 += hhi(u0.x); a2 += hlo(u0.y); a3 += hhi(u0.y);
    if (lane < 32){ unsigned w0v = *(const unsigned*)(hbb + off0 + lo4); a4 += hlo(w0v); a5 += hhi(w0v); }
  }
  const int* cc = ccnt + (size_t)v * 12;
  int4 cA = *(const int4*)cc;          // c0..c3
  int4 cB = *(const int4*)(cc + 4);    // c4..c7
  int c8 = cc[8];
  float w0f = (float)(2 * cA.x + cA.y + cA.z + cA.w + cB.z + 1);
  float w1f = (float)(cA.y + cA.w + 2 * cB.x + cB.y + cB.w);
  float w2f = (float)(cA.z + cB.y + cB.z + cB.w + 2 * c8);
  {
    const float4 e0v = *(const float4*)&se[0 * DP + 4 * lane];
    const float4 e1v = *(const float4*)&se[1 * DP + 4 * lane];
    const float4 e2v = *(const float4*)&se[2 * DP + 4 * lane];
    const float4 e4v = *(const float4*)&se[3 * DP + 4 * lane];
    a0 += w0f * e0v.x + w1f * e1v.x + w2f * e2v.x + e4v.x;
    a1 += w0f * e0v.y + w1f * e1v.y + w2f * e2v.y + e4v.y;
    a2 += w0f * e0v.z + w1f * e1v.z + w2f * e2v.z + e4v.z;
    a3 += w0f * e0v.w + w1f * e1v.w + w2f * e2v.w + e4v.w;
  }
  char* ab = (char*)agg;
  unsigned oo = (unsigned)v * 640u;
  uint2 st; st.x = packh(a0, a1); st.y = packh(a2, a3);
  *(uint2*)(ab + oo + lo8) = st;
  if (lane < 32){
    int cI = 256 + 2 * lane;
    a4 += w0f * se[0 * DP + cI]     + w1f * se[1 * DP + cI]     + w2f * se[2 * DP + cI]     + se[3 * DP + cI];
    a5 += w0f * se[0 * DP + cI + 1] + w1f * se[1 * DP + cI + 1] + w2f * se[2 * DP + cI + 1] + se[3 * DP + cI + 1];
    *(unsigned*)(ab + oo + lo4) = packh(a4, a5);
  }
}

// ---------------- fused MLP: h2 = (relu(agg@W1+b1))@W2 + b2, + BN stats ----------------
// Block: 64 rows x full width. hid lives in LDS only (XOR-swizzled).
// 8 waves = 2 row-halves (mh) x 4 col-quarters (nq). Fragments load direct global->VGPR.
__global__ __launch_bounds__(512, 4) void k_mlp(const u16* __restrict__ agg,
    const u16* __restrict__ W1t, const u16* __restrict__ W2t,
    const float* __restrict__ b1, const float* __restrict__ b2,
    float* __restrict__ h2, float* __restrict__ sums){
  __shared__ __attribute__((aligned(16))) u16 hid[MT * HP];   // 80 KB, swizzled
  const int tid = threadIdx.x;
  const int lane = tid & 63, w = tid >> 6;
  const int mh = w >> 2, nq = w & 3;
  const int r0 = blockIdx.x * MT;
  const unsigned l15 = (unsigned)(lane & 15);
  const unsigned kb16 = ((unsigned)(lane >> 4)) * 16u;   // k-chunk byte offset
  const char* aggB = (const char*)agg;
  const char* w1B  = (const char*)W1t;
  const char* w2B  = (const char*)W2t;

  // ---- phase A: hid = relu(agg[64x320] @ W1[320x640] + b1), 2 passes of 80 cols/wave ----
  const unsigned arow0 = (unsigned)(r0 + mh * 32) + l15;
  #pragma unroll
  for (int pass = 0; pass < 2; ++pass){
    const int nbase = nq * 160 + pass * 80;
    f32x4 acc[2][5] = {};
    #pragma unroll
    for (int ks = 0; ks < 10; ++ks){
      u16x8 af[2], bf[5];
      #pragma unroll
      for (int m = 0; m < 2; ++m)
        af[m] = *(const u16x8*)(aggB + (size_t)(arow0 + m * 16) * 640 + ks * 64 + kb16);
      #pragma unroll
      for (int n = 0; n < 5; ++n){
        unsigned col = (unsigned)(nbase + n * 16) + l15;
        bf[n] = *(const u16x8*)(w1B + (size_t)col * 640 + ks * 64 + kb16);
      }
      #pragma unroll
      for (int m = 0; m < 2; ++m)
        #pragma unroll
        for (int n = 0; n < 5; ++n)
          acc[m][n] = mfma_f16(af[m], bf[n], acc[m][n]);
    }
    #pragma unroll
    for (int m = 0; m < 2; ++m){
      #pragma unroll
      for (int n = 0; n < 5; ++n){
        const int col = nbase + n * 16 + (int)l15;
        const float bv = (col < 600) ? b1[col] : 0.f;
        #pragma unroll
        for (int r = 0; r < 4; ++r){
          const unsigned row = (unsigned)(mh * 32 + m * 16) + ((unsigned)(lane >> 4)) * 4u + (unsigned)r;
          const float vv = fmaxf(acc[m][n][r] + bv, 0.f);
          const unsigned byte = row * 1280u + ((2u * (unsigned)col) ^ ((row & 7u) << 4));
          *(u16*)((char*)hid + byte) = f2h(vv);
        }
      }
    }
  }
  __syncthreads();

  // ---- phase B: h2 = hid[64x640] @ W2[640x320] + b2 ----
  f32x4 acc[2][5] = {};
  #pragma unroll
  for (int ks = 0; ks < 20; ++ks){
    u16x8 af[2], bf[5];
    #pragma unroll
    for (int m = 0; m < 2; ++m){
      const unsigned row = (unsigned)(mh * 32 + m * 16) + l15;
      const unsigned byte = row * 1280u + (((unsigned)ks * 64u + kb16) ^ ((row & 7u) << 4));
      af[m] = *(const u16x8*)((const char*)hid + byte);
    }
    #pragma unroll
    for (int n = 0; n < 5; ++n){
      const unsigned col = (unsigned)(nq * 80 + n * 16) + l15;
      bf[n] = *(const u16x8*)(w2B + (size_t)col * 1280 + ks * 64 + kb16);
    }
    #pragma unroll
    for (int m = 0; m < 2; ++m)
      #pragma unroll
      for (int n = 0; n < 5; ++n)
        acc[m][n] = mfma_f16(af[m], bf[n], acc[m][n]);
  }
  // epilogue: bias, fp32 write to h2 (cols<300, rows<NN), fused BN stats
  float sn[5] = {0,0,0,0,0}, qn[5] = {0,0,0,0,0};
  #pragma unroll
  for (int m = 0; m < 2; ++m){
    const int row0 = r0 + mh * 32 + m * 16 + (lane >> 4) * 4;
    #pragma unroll
    for (int n = 0; n < 5; ++n){
      const int col = nq * 80 + n * 16 + (int)l15;
      if (col >= D) continue;
      const float bv = b2[col];
      #pragma unroll
      for (int r = 0; r < 4; ++r){
        const int row = row0 + r;
        if (row < NN){
          const float vv = acc[m][n][r] + bv;
          h2[(size_t)row * D + col] = vv;
          sn[n] += vv; qn[n] += vv * vv;
        }
      }
    }
  }
  #pragma unroll
  for (int n = 0; n < 5; ++n){
    const int col = nq * 80 + n * 16 + (int)l15;
    float s = sn[n], q = qn[n];
    s += __shfl_xor(s, 16); q += __shfl_xor(q, 16);
    s += __shfl_xor(s, 32); q += __shfl_xor(q, 32);
    if (col < D && (lane >> 4) == 0){
      atomicAdd(&sums[col], s);
      atomicAdd(&sums[DP + col], q);
    }
  }
}

// ---------------- BatchNorm apply ----------------
template<bool LAST>
__global__ void k_bnapply(const float* h2, const float* __restrict__ sums,
    const float* __restrict__ gamma, const float* __restrict__ beta,
    u16* __restrict__ hb, float* outp){
  int r = blockIdx.x, c = threadIdx.x;   // block = DP
  float y = 0.f;
  if (c < D){
    float mu  = sums[c] * (1.f / NN);
    float var = sums[DP + c] * (1.f / NN) - mu * mu;
    float x = h2[(size_t)r * D + c];
    float s = var + 1e-5f;
    float inv = rsqrtf(s);
    inv = inv * (1.5f - 0.5f * s * inv * inv);   // Newton: full fp32 accuracy
    y = (x - mu) * inv * gamma[c] + beta[c];
    if (!LAST) y = fmaxf(y, 0.f);
  }
  if (LAST){ if (c < D) outp[(size_t)r * D + c] = y; }
  else hb[(size_t)r * DP + c] = f2h(y);    // pad cols -> 0
}

extern "C" void kernel_launch(void* const* d_in, const int* in_sizes, int n_in,
                              void* d_out, int out_size, void* d_ws, size_t ws_size,
                              hipStream_t stream){
  (void)in_sizes; (void)n_in; (void)out_size; (void)ws_size;
  const int*   x    = (const int*)d_in[0];
  const int*   ei   = (const int*)d_in[1];
  const int*   ea   = (const int*)d_in[2];
  const float* xemb = (const float*)d_in[3];
  const float* eemb = (const float*)d_in[4];
  const float* W1   = (const float*)d_in[5];
  const float* b1   = (const float*)d_in[6];
  const float* W2   = (const float*)d_in[7];
  const float* b2   = (const float*)d_in[8];
  const float* gam  = (const float*)d_in[9];
  const float* bet  = (const float*)d_in[10];
  float* out = (float*)d_out;

  char* w = (char*)d_ws;
  size_t off = 0;
  auto alloc = [&](size_t b){ void* p = w + off; off += (b + 255) & ~(size_t)255; return p; };
  u16* hb    = (u16*)alloc((size_t)NROWPAD * DP * 2);   // 32 MB
  u16* aggb  = (u16*)alloc((size_t)NROWPAD * DP * 2);   // 32 MB (padded rows for k_mlp frag loads)
  u16* W1t   = (u16*)alloc((size_t)5 * HP * DP * 2);    // 2 MB
  u16* W2t   = (u16*)alloc((size_t)5 * DP * HP * 2);    // 2 MB
  int* rp    = (int*)alloc((NN + 1) * 4);
  int* cnt   = (int*)alloc((size_t)NN * 4);
  int* cur   = (int*)alloc((size_t)NN * 4);
  int* bsum  = (int*)alloc(64 * 4);
  int* pack  = (int*)alloc((size_t)NE * 4);
  int* ccnt  = (int*)alloc((size_t)NN * 12 * 4);        // 2.4 MB
  float* sums= (float*)alloc(2 * DP * 4);
  float* h2  = out;   // reuse d_out as [NN][300] fp32 activation buffer

  hipMemsetAsync(cnt, 0, NN * 4, stream);
  hipMemsetAsync(ccnt, 0, (size_t)NN * 12 * 4, stream);
  k_count<<<NE / 256, 256, 0, stream>>>(ei, ea, cnt, ccnt);
  k_scan1<<<(NN + 1023) / 1024, 1024, 0, stream>>>(cnt, rp, bsum);
  k_scan2<<<1, 64, 0, stream>>>(bsum, (NN + 1023) / 1024);
  k_scan3<<<(NN + 255) / 256, 256, 0, stream>>>(rp, cur, bsum);
  k_fill<<<NE / 256, 256, 0, stream>>>(ei, cur, pack);
  k_wconv<<<(5 * HP * DP) / 256, 256, 0, stream>>>(W1, W2, W1t, W2t);
  k_nodeemb<<<NN, DP, 0, stream>>>(x, xemb, hb);

  for (int l = 0; l < 5; ++l){
    k_agg<<<(NN + 3) / 4, 256, 0, stream>>>(hb, rp, pack, ccnt, eemb + (size_t)l * 6 * D, aggb);
    hipMemsetAsync(sums, 0, 2 * DP * 4, stream);
    k_mlp<<<NROWPAD / MT, 512, 0, stream>>>(aggb,
        W1t + (size_t)l * HP * DP, W2t + (size_t)l * DP * HP,
        b1 + l * 600, b2 + l * D, h2, sums);
    if (l < 4) k_bnapply<false><<<NN, DP, 0, stream>>>(h2, sums, gam + l * D, bet + l * D, hb, nullptr);
    else       k_bnapply<true ><<<NN, DP, 0, stream>>>(h2, sums, gam + l * D, bet + l * D, nullptr, out);
  }
}

// Round 6
// 1998.740 us; speedup vs baseline: 1.0030x; 1.0030x over previous
//
#include <hip/hip_runtime.h>
#include <hip/hip_bf16.h>

typedef unsigned short u16;
typedef _Float16 f16;
typedef f16 f16x8 __attribute__((ext_vector_type(8)));
typedef f16 half2t __attribute__((ext_vector_type(2)));
typedef u16 u16x8 __attribute__((ext_vector_type(8)));
typedef float f32x4 __attribute__((ext_vector_type(4)));

#define NN 50000
#define NE 800000
#define D  300
#define DP 320   // padded feature dim
#define HP 640   // padded hidden dim
#define MT 64    // rows per k_mlp block
#define NROWPAD 50048

__device__ __forceinline__ float h2f(u16 u){ f16 h = __builtin_bit_cast(f16, u); return (float)h; }
__device__ __forceinline__ u16 f2h(float f){ f16 h = (f16)f; return __builtin_bit_cast(u16, h); }
__device__ __forceinline__ float hlo(unsigned u){ half2t h = __builtin_bit_cast(half2t, u); return (float)h.x; }
__device__ __forceinline__ float hhi(unsigned u){ half2t h = __builtin_bit_cast(half2t, u); return (float)h.y; }
__device__ __forceinline__ unsigned packh(float x, float y){ half2t h; h.x = (f16)x; h.y = (f16)y; return __builtin_bit_cast(unsigned, h); }

__device__ __forceinline__ f32x4 mfma_f16(u16x8 a, u16x8 b, f32x4 c){
  return __builtin_amdgcn_mfma_f32_16x16x32_f16(__builtin_bit_cast(f16x8, a),
                                                __builtin_bit_cast(f16x8, b), c, 0, 0, 0);
}

// ---------------- CSR build (by dst) + per-(dst,combo) counts ----------------
__global__ void k_count(const int* __restrict__ ei, const int* __restrict__ ea,
                        int* __restrict__ cnt, int* __restrict__ ccnt){
  int e = blockIdx.x * 256 + threadIdx.x;
  if (e < NE){
    int d = ei[NE + e];
    atomicAdd(&cnt[d], 1);
    int t = ea[2*e] * 3 + ea[2*e + 1];     // attrs in [0,3)
    atomicAdd(&ccnt[d * 12 + t], 1);
  }
}

__global__ void k_scan1(const int* __restrict__ cnt, int* __restrict__ rp, int* __restrict__ bsum){
  __shared__ int s[1024];
  int i = blockIdx.x * 1024 + threadIdx.x;
  int v = (i < NN) ? cnt[i] : 0;
  s[threadIdx.x] = v;
  __syncthreads();
  for (int off = 1; off < 1024; off <<= 1){
    int t = (threadIdx.x >= off) ? s[threadIdx.x - off] : 0;
    __syncthreads();
    s[threadIdx.x] += t;
    __syncthreads();
  }
  if (i < NN) rp[i] = s[threadIdx.x] - v;
  if (threadIdx.x == 1023) bsum[blockIdx.x] = s[1023];
}

__global__ void k_scan2(int* __restrict__ bsum, int nb){
  __shared__ int s[64];
  int v = (threadIdx.x < nb) ? bsum[threadIdx.x] : 0;
  s[threadIdx.x] = v; __syncthreads();
  for (int off = 1; off < 64; off <<= 1){
    int t = (threadIdx.x >= off) ? s[threadIdx.x - off] : 0;
    __syncthreads();
    s[threadIdx.x] += t;
    __syncthreads();
  }
  if (threadIdx.x < nb) bsum[threadIdx.x] = s[threadIdx.x] - v;
}

__global__ void k_scan3(int* __restrict__ rp, int* __restrict__ cur, const int* __restrict__ bsum){
  int i = blockIdx.x * 256 + threadIdx.x;
  if (i < NN){ int v = rp[i] + bsum[i >> 10]; rp[i] = v; cur[i] = v; }
  if (i == 0) rp[NN] = NE;
}

__global__ void k_fill(const int* __restrict__ ei, int* __restrict__ cur, int* __restrict__ pack){
  int e = blockIdx.x * 256 + threadIdx.x;
  if (e >= NE) return;
  int d = ei[NE + e];
  int pos = atomicAdd(&cur[d], 1);
  pack[pos] = ei[e];                       // src only
}

// ---------------- weight transpose + pad -> fp16 ----------------
__global__ void k_wconv(const float* __restrict__ W1, const float* __restrict__ W2,
                        u16* __restrict__ W1t, u16* __restrict__ W2t){
  int i = blockIdx.x * 256 + threadIdx.x;
  {
    int l = i / (HP * DP); int rem = i % (HP * DP); int n = rem / DP, k = rem % DP;
    float v = (n < 600 && k < D) ? W1[((size_t)l * D + k) * 600 + n] : 0.f;
    W1t[i] = f2h(v);
  }
  {
    int l = i / (DP * HP); int rem = i % (DP * HP); int n = rem / HP, k = rem % HP;
    float v = (n < D && k < 600) ? W2[((size_t)l * 600 + k) * D + n] : 0.f;
    W2t[i] = f2h(v);
  }
}

// ---------------- node embedding -> fp16 padded ----------------
__global__ void k_nodeemb(const int* __restrict__ x, const float* __restrict__ xemb, u16* __restrict__ hb){
  int v = blockIdx.x, c = threadIdx.x;  // block = DP threads
  float y = 0.f;
  if (c < D){
    int a = x[2*v], b = x[2*v + 1];
    y = xemb[(size_t)a * D + c] + xemb[(size_t)b * D + c];
  }
  hb[(size_t)v * DP + c] = f2h(y);
}

// ---------------- per-layer aggregation: one wave per node ----------------
__global__ __launch_bounds__(256) void k_agg(const u16* __restrict__ hb, const int* __restrict__ rp,
    const int* __restrict__ pack, const int* __restrict__ ccnt,
    const float* __restrict__ eemb, u16* __restrict__ agg){
  __shared__ float se[4 * DP];   // rows e0,e1,e2,e4 (fp32)
  for (int i = threadIdx.x; i < 4 * DP; i += 256){
    int t = i / DP, c = i % DP;
    int row = (t == 3) ? 4 : t;
    se[i] = (c < D) ? eemb[row * D + c] : 0.f;
  }
  __syncthreads();
  const int wid = threadIdx.x >> 6, lane = threadIdx.x & 63;
  const int v = blockIdx.x * 4 + wid;
  if (v >= NN) return;
  const char* __restrict__ hbb = (const char*)hb;
  const unsigned lo8 = (unsigned)lane * 8u;          // cols 4l..4l+3
  const unsigned lo4 = 512u + (unsigned)lane * 4u;   // cols 256+2l (lanes<32)
  float a0, a1, a2, a3, a4 = 0.f, a5 = 0.f;
  {
    unsigned off = (unsigned)v * 640u;
    uint2 u = *(const uint2*)(hbb + off + lo8);
    a0 = hlo(u.x); a1 = hhi(u.x); a2 = hlo(u.y); a3 = hhi(u.y);
    if (lane < 32){ unsigned uw = *(const unsigned*)(hbb + off + lo4); a4 = hlo(uw); a5 = hhi(uw); }
  }
  int p = rp[v];
  const int pe = rp[v + 1];
  for (; p + 2 <= pe; p += 2){
    unsigned off0 = (unsigned)pack[p] * 640u;
    unsigned off1 = (unsigned)pack[p + 1] * 640u;
    uint2 u0 = *(const uint2*)(hbb + off0 + lo8);
    uint2 u1 = *(const uint2*)(hbb + off1 + lo8);
    unsigned w0v = 0, w1v = 0;
    if (lane < 32){
      w0v = *(const unsigned*)(hbb + off0 + lo4);
      w1v = *(const unsigned*)(hbb + off1 + lo4);
    }
    a0 += hlo(u0.x) + hlo(u1.x);
    a1 += hhi(u0.x) + hhi(u1.x);
    a2 += hlo(u0.y) + hlo(u1.y);
    a3 += hhi(u0.y) + hhi(u1.y);
    a4 += hlo(w0v) + hlo(w1v);
    a5 += hhi(w0v) + hhi(w1v);
  }
  if (p < pe){
    unsigned off0 = (unsigned)pack[p] * 640u;
    uint2 u0 = *(const uint2*)(hbb + off0 + lo8);
    a0 += hlo(u0.x); a1 += hhi(u0.x); a2 += hlo(u0.y); a3 += hhi(u0.y);
    if (lane < 32){ unsigned w0v = *(const unsigned*)(hbb + off0 + lo4); a4 += hlo(w0v); a5 += hhi(w0v); }
  }
  const int* cc = ccnt + (size_t)v * 12;
  int4 cA = *(const int4*)cc;          // c0..c3
  int4 cB = *(const int4*)(cc + 4);    // c4..c7
  int c8 = cc[8];
  float w0f = (float)(2 * cA.x + cA.y + cA.z + cA.w + cB.z + 1);
  float w1f = (float)(cA.y + cA.w + 2 * cB.x + cB.y + cB.w);
  float w2f = (float)(cA.z + cB.y + cB.z + cB.w + 2 * c8);
  {
    const float4 e0v = *(const float4*)&se[0 * DP + 4 * lane];
    const float4 e1v = *(const float4*)&se[1 * DP + 4 * lane];
    const float4 e2v = *(const float4*)&se[2 * DP + 4 * lane];
    const float4 e4v = *(const float4*)&se[3 * DP + 4 * lane];
    a0 += w0f * e0v.x + w1f * e1v.x + w2f * e2v.x + e4v.x;
    a1 += w0f * e0v.y + w1f * e1v.y + w2f * e2v.y + e4v.y;
    a2 += w0f * e0v.z + w1f * e1v.z + w2f * e2v.z + e4v.z;
    a3 += w0f * e0v.w + w1f * e1v.w + w2f * e2v.w + e4v.w;
  }
  char* ab = (char*)agg;
  unsigned oo = (unsigned)v * 640u;
  uint2 st; st.x = packh(a0, a1); st.y = packh(a2, a3);
  *(uint2*)(ab + oo + lo8) = st;
  if (lane < 32){
    int cI = 256 + 2 * lane;
    a4 += w0f * se[0 * DP + cI]     + w1f * se[1 * DP + cI]     + w2f * se[2 * DP + cI]     + se[3 * DP + cI];
    a5 += w0f * se[0 * DP + cI + 1] + w1f * se[1 * DP + cI + 1] + w2f * se[2 * DP + cI + 1] + se[3 * DP + cI + 1];
    *(unsigned*)(ab + oo + lo4) = packh(a4, a5);
  }
}

// ---------------- fused MLP: h2 = (relu(agg@W1+b1))@W2 + b2, + BN stats ----------------
// Block: 64 rows x full width. hid lives in LDS only (XOR-swizzled).
// 8 waves = 2 row-halves (mh) x 4 col-quarters (nq). Fragments load direct global->VGPR.
// NOTE: min-waves=2 (not 4): VGPR cap 256 so ~28 VGPRs of loads/iter stay in flight.
// Round-5 lesson: (512,4) forced VGPR=64 -> zero ILP -> 244us latency-bound.
__global__ __launch_bounds__(512, 2) void k_mlp(const u16* __restrict__ agg,
    const u16* __restrict__ W1t, const u16* __restrict__ W2t,
    const float* __restrict__ b1, const float* __restrict__ b2,
    float* __restrict__ h2, float* __restrict__ sums){
  __shared__ __attribute__((aligned(16))) u16 hid[MT * HP];   // 80 KB, swizzled
  const int tid = threadIdx.x;
  const int lane = tid & 63, w = tid >> 6;
  const int mh = w >> 2, nq = w & 3;
  const int r0 = blockIdx.x * MT;
  const unsigned l15 = (unsigned)(lane & 15);
  const unsigned kb16 = ((unsigned)(lane >> 4)) * 16u;   // k-chunk byte offset
  const char* aggB = (const char*)agg;
  const char* w1B  = (const char*)W1t;
  const char* w2B  = (const char*)W2t;

  // ---- phase A: hid = relu(agg[64x320] @ W1[320x640] + b1), 2 passes of 80 cols/wave ----
  const unsigned arow0 = (unsigned)(r0 + mh * 32) + l15;
  #pragma unroll
  for (int pass = 0; pass < 2; ++pass){
    const int nbase = nq * 160 + pass * 80;
    f32x4 acc[2][5] = {};
    #pragma unroll
    for (int ks = 0; ks < 10; ++ks){
      u16x8 af[2], bf[5];
      #pragma unroll
      for (int m = 0; m < 2; ++m)
        af[m] = *(const u16x8*)(aggB + (size_t)(arow0 + m * 16) * 640 + ks * 64 + kb16);
      #pragma unroll
      for (int n = 0; n < 5; ++n){
        unsigned col = (unsigned)(nbase + n * 16) + l15;
        bf[n] = *(const u16x8*)(w1B + (size_t)col * 640 + ks * 64 + kb16);
      }
      #pragma unroll
      for (int m = 0; m < 2; ++m)
        #pragma unroll
        for (int n = 0; n < 5; ++n)
          acc[m][n] = mfma_f16(af[m], bf[n], acc[m][n]);
    }
    #pragma unroll
    for (int m = 0; m < 2; ++m){
      #pragma unroll
      for (int n = 0; n < 5; ++n){
        const int col = nbase + n * 16 + (int)l15;
        const float bv = (col < 600) ? b1[col] : 0.f;
        #pragma unroll
        for (int r = 0; r < 4; ++r){
          const unsigned row = (unsigned)(mh * 32 + m * 16) + ((unsigned)(lane >> 4)) * 4u + (unsigned)r;
          const float vv = fmaxf(acc[m][n][r] + bv, 0.f);
          const unsigned byte = row * 1280u + ((2u * (unsigned)col) ^ ((row & 7u) << 4));
          *(u16*)((char*)hid + byte) = f2h(vv);
        }
      }
    }
  }
  __syncthreads();

  // ---- phase B: h2 = hid[64x640] @ W2[640x320] + b2 ----
  f32x4 acc[2][5] = {};
  #pragma unroll
  for (int ks = 0; ks < 20; ++ks){
    u16x8 af[2], bf[5];
    #pragma unroll
    for (int m = 0; m < 2; ++m){
      const unsigned row = (unsigned)(mh * 32 + m * 16) + l15;
      const unsigned byte = row * 1280u + (((unsigned)ks * 64u + kb16) ^ ((row & 7u) << 4));
      af[m] = *(const u16x8*)((const char*)hid + byte);
    }
    #pragma unroll
    for (int n = 0; n < 5; ++n){
      const unsigned col = (unsigned)(nq * 80 + n * 16) + l15;
      bf[n] = *(const u16x8*)(w2B + (size_t)col * 1280 + ks * 64 + kb16);
    }
    #pragma unroll
    for (int m = 0; m < 2; ++m)
      #pragma unroll
      for (int n = 0; n < 5; ++n)
        acc[m][n] = mfma_f16(af[m], bf[n], acc[m][n]);
  }
  // epilogue: bias, fp32 write to h2 (cols<300, rows<NN), fused BN stats
  float sn[5] = {0,0,0,0,0}, qn[5] = {0,0,0,0,0};
  #pragma unroll
  for (int m = 0; m < 2; ++m){
    const int row0 = r0 + mh * 32 + m * 16 + (lane >> 4) * 4;
    #pragma unroll
    for (int n = 0; n < 5; ++n){
      const int col = nq * 80 + n * 16 + (int)l15;
      if (col >= D) continue;
      const float bv = b2[col];
      #pragma unroll
      for (int r = 0; r < 4; ++r){
        const int row = row0 + r;
        if (row < NN){
          const float vv = acc[m][n][r] + bv;
          h2[(size_t)row * D + col] = vv;
          sn[n] += vv; qn[n] += vv * vv;
        }
      }
    }
  }
  #pragma unroll
  for (int n = 0; n < 5; ++n){
    const int col = nq * 80 + n * 16 + (int)l15;
    float s = sn[n], q = qn[n];
    s += __shfl_xor(s, 16); q += __shfl_xor(q, 16);
    s += __shfl_xor(s, 32); q += __shfl_xor(q, 32);
    if (col < D && (lane >> 4) == 0){
      atomicAdd(&sums[col], s);
      atomicAdd(&sums[DP + col], q);
    }
  }
}

// ---------------- BatchNorm apply ----------------
template<bool LAST>
__global__ void k_bnapply(const float* h2, const float* __restrict__ sums,
    const float* __restrict__ gamma, const float* __restrict__ beta,
    u16* __restrict__ hb, float* outp){
  int r = blockIdx.x, c = threadIdx.x;   // block = DP
  float y = 0.f;
  if (c < D){
    float mu  = sums[c] * (1.f / NN);
    float var = sums[DP + c] * (1.f / NN) - mu * mu;
    float x = h2[(size_t)r * D + c];
    float s = var + 1e-5f;
    float inv = rsqrtf(s);
    inv = inv * (1.5f - 0.5f * s * inv * inv);   // Newton: full fp32 accuracy
    y = (x - mu) * inv * gamma[c] + beta[c];
    if (!LAST) y = fmaxf(y, 0.f);
  }
  if (LAST){ if (c < D) outp[(size_t)r * D + c] = y; }
  else hb[(size_t)r * DP + c] = f2h(y);    // pad cols -> 0
}

extern "C" void kernel_launch(void* const* d_in, const int* in_sizes, int n_in,
                              void* d_out, int out_size, void* d_ws, size_t ws_size,
                              hipStream_t stream){
  (void)in_sizes; (void)n_in; (void)out_size; (void)ws_size;
  const int*   x    = (const int*)d_in[0];
  const int*   ei   = (const int*)d_in[1];
  const int*   ea   = (const int*)d_in[2];
  const float* xemb = (const float*)d_in[3];
  const float* eemb = (const float*)d_in[4];
  const float* W1   = (const float*)d_in[5];
  const float* b1   = (const float*)d_in[6];
  const float* W2   = (const float*)d_in[7];
  const float* b2   = (const float*)d_in[8];
  const float* gam  = (const float*)d_in[9];
  const float* bet  = (const float*)d_in[10];
  float* out = (float*)d_out;

  char* w = (char*)d_ws;
  size_t off = 0;
  auto alloc = [&](size_t b){ void* p = w + off; off += (b + 255) & ~(size_t)255; return p; };
  u16* hb    = (u16*)alloc((size_t)NROWPAD * DP * 2);   // 32 MB
  u16* aggb  = (u16*)alloc((size_t)NROWPAD * DP * 2);   // 32 MB (padded rows for k_mlp frag loads)
  u16* W1t   = (u16*)alloc((size_t)5 * HP * DP * 2);    // 2 MB
  u16* W2t   = (u16*)alloc((size_t)5 * DP * HP * 2);    // 2 MB
  int* rp    = (int*)alloc((NN + 1) * 4);
  int* cnt   = (int*)alloc((size_t)NN * 4);
  int* cur   = (int*)alloc((size_t)NN * 4);
  int* bsum  = (int*)alloc(64 * 4);
  int* pack  = (int*)alloc((size_t)NE * 4);
  int* ccnt  = (int*)alloc((size_t)NN * 12 * 4);        // 2.4 MB
  float* sums5 = (float*)alloc(5 * 2 * DP * 4);         // per-layer BN stat buffers
  float* h2  = out;   // reuse d_out as [NN][300] fp32 activation buffer

  hipMemsetAsync(cnt, 0, NN * 4, stream);
  hipMemsetAsync(ccnt, 0, (size_t)NN * 12 * 4, stream);
  hipMemsetAsync(sums5, 0, 5 * 2 * DP * 4, stream);
  k_count<<<NE / 256, 256, 0, stream>>>(ei, ea, cnt, ccnt);
  k_scan1<<<(NN + 1023) / 1024, 1024, 0, stream>>>(cnt, rp, bsum);
  k_scan2<<<1, 64, 0, stream>>>(bsum, (NN + 1023) / 1024);
  k_scan3<<<(NN + 255) / 256, 256, 0, stream>>>(rp, cur, bsum);
  k_fill<<<NE / 256, 256, 0, stream>>>(ei, cur, pack);
  k_wconv<<<(5 * HP * DP) / 256, 256, 0, stream>>>(W1, W2, W1t, W2t);
  k_nodeemb<<<NN, DP, 0, stream>>>(x, xemb, hb);

  for (int l = 0; l < 5; ++l){
    float* sums = sums5 + l * 2 * DP;
    k_agg<<<(NN + 3) / 4, 256, 0, stream>>>(hb, rp, pack, ccnt, eemb + (size_t)l * 6 * D, aggb);
    k_mlp<<<NROWPAD / MT, 512, 0, stream>>>(aggb,
        W1t + (size_t)l * HP * DP, W2t + (size_t)l * DP * HP,
        b1 + l * 600, b2 + l * D, h2, sums);
    if (l < 4) k_bnapply<false><<<NN, DP, 0, stream>>>(h2, sums, gam + l * D, bet + l * D, hb, nullptr);
    else       k_bnapply<true ><<<NN, DP, 0, stream>>>(h2, sums, gam + l * D, bet + l * D, nullptr, out);
  }
}

// Round 7
// 1697.016 us; speedup vs baseline: 1.1814x; 1.1778x over previous
//
#include <hip/hip_runtime.h>
#include <hip/hip_bf16.h>

typedef unsigned short u16;
typedef _Float16 f16;
typedef f16 f16x8 __attribute__((ext_vector_type(8)));
typedef f16 half2t __attribute__((ext_vector_type(2)));
typedef u16 u16x8 __attribute__((ext_vector_type(8)));
typedef float f32x4 __attribute__((ext_vector_type(4)));

#define NN 50000
#define NE 800000
#define D  300
#define DP 320   // padded feature dim
#define HP 640   // padded hidden dim
#define MT 32    // rows per k_mlp block
#define NROWPAD 50048

__device__ __forceinline__ float h2f(u16 u){ f16 h = __builtin_bit_cast(f16, u); return (float)h; }
__device__ __forceinline__ u16 f2h(float f){ f16 h = (f16)f; return __builtin_bit_cast(u16, h); }
__device__ __forceinline__ float hlo(unsigned u){ half2t h = __builtin_bit_cast(half2t, u); return (float)h.x; }
__device__ __forceinline__ float hhi(unsigned u){ half2t h = __builtin_bit_cast(half2t, u); return (float)h.y; }
__device__ __forceinline__ unsigned packh(float x, float y){ half2t h; h.x = (f16)x; h.y = (f16)y; return __builtin_bit_cast(unsigned, h); }

__device__ __forceinline__ void gl_lds16(const void* g, void* l){
  __builtin_amdgcn_global_load_lds((const __attribute__((address_space(1))) unsigned int*)g,
                                   (__attribute__((address_space(3))) unsigned int*)l, 16, 0, 0);
}

__device__ __forceinline__ f32x4 mfma_f16(u16x8 a, u16x8 b, f32x4 c){
  return __builtin_amdgcn_mfma_f32_16x16x32_f16(__builtin_bit_cast(f16x8, a),
                                                __builtin_bit_cast(f16x8, b), c, 0, 0, 0);
}

// ---------------- CSR build (by dst) + per-(dst,combo) counts ----------------
__global__ void k_count(const int* __restrict__ ei, const int* __restrict__ ea,
                        int* __restrict__ cnt, int* __restrict__ ccnt){
  int e = blockIdx.x * 256 + threadIdx.x;
  if (e < NE){
    int d = ei[NE + e];
    atomicAdd(&cnt[d], 1);
    int t = ea[2*e] * 3 + ea[2*e + 1];     // attrs in [0,3)
    atomicAdd(&ccnt[d * 12 + t], 1);
  }
}

__global__ void k_scan1(const int* __restrict__ cnt, int* __restrict__ rp, int* __restrict__ bsum){
  __shared__ int s[1024];
  int i = blockIdx.x * 1024 + threadIdx.x;
  int v = (i < NN) ? cnt[i] : 0;
  s[threadIdx.x] = v;
  __syncthreads();
  for (int off = 1; off < 1024; off <<= 1){
    int t = (threadIdx.x >= off) ? s[threadIdx.x - off] : 0;
    __syncthreads();
    s[threadIdx.x] += t;
    __syncthreads();
  }
  if (i < NN) rp[i] = s[threadIdx.x] - v;
  if (threadIdx.x == 1023) bsum[blockIdx.x] = s[1023];
}

__global__ void k_scan2(int* __restrict__ bsum, int nb){
  __shared__ int s[64];
  int v = (threadIdx.x < nb) ? bsum[threadIdx.x] : 0;
  s[threadIdx.x] = v; __syncthreads();
  for (int off = 1; off < 64; off <<= 1){
    int t = (threadIdx.x >= off) ? s[threadIdx.x - off] : 0;
    __syncthreads();
    s[threadIdx.x] += t;
    __syncthreads();
  }
  if (threadIdx.x < nb) bsum[threadIdx.x] = s[threadIdx.x] - v;
}

__global__ void k_scan3(int* __restrict__ rp, int* __restrict__ cur, const int* __restrict__ bsum){
  int i = blockIdx.x * 256 + threadIdx.x;
  if (i < NN){ int v = rp[i] + bsum[i >> 10]; rp[i] = v; cur[i] = v; }
  if (i == 0) rp[NN] = NE;
}

__global__ void k_fill(const int* __restrict__ ei, int* __restrict__ cur, int* __restrict__ pack){
  int e = blockIdx.x * 256 + threadIdx.x;
  if (e >= NE) return;
  int d = ei[NE + e];
  int pos = atomicAdd(&cur[d], 1);
  pack[pos] = ei[e];                       // src only
}

// ---------------- weight transpose + pad -> fp16 ----------------
__global__ void k_wconv(const float* __restrict__ W1, const float* __restrict__ W2,
                        u16* __restrict__ W1t, u16* __restrict__ W2t){
  int i = blockIdx.x * 256 + threadIdx.x;
  {
    int l = i / (HP * DP); int rem = i % (HP * DP); int n = rem / DP, k = rem % DP;
    float v = (n < 600 && k < D) ? W1[((size_t)l * D + k) * 600 + n] : 0.f;
    W1t[i] = f2h(v);
  }
  {
    int l = i / (DP * HP); int rem = i % (DP * HP); int n = rem / HP, k = rem % HP;
    float v = (n < D && k < 600) ? W2[((size_t)l * 600 + k) * D + n] : 0.f;
    W2t[i] = f2h(v);
  }
}

// ---------------- node embedding -> fp16 padded ----------------
__global__ void k_nodeemb(const int* __restrict__ x, const float* __restrict__ xemb, u16* __restrict__ hb){
  int v = blockIdx.x, c = threadIdx.x;  // block = DP threads
  float y = 0.f;
  if (c < D){
    int a = x[2*v], b = x[2*v + 1];
    y = xemb[(size_t)a * D + c] + xemb[(size_t)b * D + c];
  }
  hb[(size_t)v * DP + c] = f2h(y);
}

// ---------------- per-layer aggregation: one wave per node ----------------
__global__ __launch_bounds__(256) void k_agg(const u16* __restrict__ hb, const int* __restrict__ rp,
    const int* __restrict__ pack, const int* __restrict__ ccnt,
    const float* __restrict__ eemb, u16* __restrict__ agg){
  __shared__ float se[4 * DP];   // rows e0,e1,e2,e4 (fp32)
  for (int i = threadIdx.x; i < 4 * DP; i += 256){
    int t = i / DP, c = i % DP;
    int row = (t == 3) ? 4 : t;
    se[i] = (c < D) ? eemb[row * D + c] : 0.f;
  }
  __syncthreads();
  const int wid = threadIdx.x >> 6, lane = threadIdx.x & 63;
  const int v = blockIdx.x * 4 + wid;
  if (v >= NN) return;
  const char* __restrict__ hbb = (const char*)hb;
  const unsigned lo8 = (unsigned)lane * 8u;          // cols 4l..4l+3
  const unsigned lo4 = 512u + (unsigned)lane * 4u;   // cols 256+2l (lanes<32)
  float a0, a1, a2, a3, a4 = 0.f, a5 = 0.f;
  {
    unsigned off = (unsigned)v * 640u;
    uint2 u = *(const uint2*)(hbb + off + lo8);
    a0 = hlo(u.x); a1 = hhi(u.x); a2 = hlo(u.y); a3 = hhi(u.y);
    if (lane < 32){ unsigned uw = *(const unsigned*)(hbb + off + lo4); a4 = hlo(uw); a5 = hhi(uw); }
  }
  int p = rp[v];
  const int pe = rp[v + 1];
  for (; p + 2 <= pe; p += 2){
    unsigned off0 = (unsigned)pack[p] * 640u;
    unsigned off1 = (unsigned)pack[p + 1] * 640u;
    uint2 u0 = *(const uint2*)(hbb + off0 + lo8);
    uint2 u1 = *(const uint2*)(hbb + off1 + lo8);
    unsigned w0v = 0, w1v = 0;
    if (lane < 32){
      w0v = *(const unsigned*)(hbb + off0 + lo4);
      w1v = *(const unsigned*)(hbb + off1 + lo4);
    }
    a0 += hlo(u0.x) + hlo(u1.x);
    a1 += hhi(u0.x) + hhi(u1.x);
    a2 += hlo(u0.y) + hlo(u1.y);
    a3 += hhi(u0.y) + hhi(u1.y);
    a4 += hlo(w0v) + hlo(w1v);
    a5 += hhi(w0v) + hhi(w1v);
  }
  if (p < pe){
    unsigned off0 = (unsigned)pack[p] * 640u;
    uint2 u0 = *(const uint2*)(hbb + off0 + lo8);
    a0 += hlo(u0.x); a1 += hhi(u0.x); a2 += hlo(u0.y); a3 += hhi(u0.y);
    if (lane < 32){ unsigned w0v = *(const unsigned*)(hbb + off0 + lo4); a4 += hlo(w0v); a5 += hhi(w0v); }
  }
  const int* cc = ccnt + (size_t)v * 12;
  int4 cA = *(const int4*)cc;          // c0..c3
  int4 cB = *(const int4*)(cc + 4);    // c4..c7
  int c8 = cc[8];
  float w0f = (float)(2 * cA.x + cA.y + cA.z + cA.w + cB.z + 1);
  float w1f = (float)(cA.y + cA.w + 2 * cB.x + cB.y + cB.w);
  float w2f = (float)(cA.z + cB.y + cB.z + cB.w + 2 * c8);
  {
    const float4 e0v = *(const float4*)&se[0 * DP + 4 * lane];
    const float4 e1v = *(const float4*)&se[1 * DP + 4 * lane];
    const float4 e2v = *(const float4*)&se[2 * DP + 4 * lane];
    const float4 e4v = *(const float4*)&se[3 * DP + 4 * lane];
    a0 += w0f * e0v.x + w1f * e1v.x + w2f * e2v.x + e4v.x;
    a1 += w0f * e0v.y + w1f * e1v.y + w2f * e2v.y + e4v.y;
    a2 += w0f * e0v.z + w1f * e1v.z + w2f * e2v.z + e4v.z;
    a3 += w0f * e0v.w + w1f * e1v.w + w2f * e2v.w + e4v.w;
  }
  char* ab = (char*)agg;
  unsigned oo = (unsigned)v * 640u;
  uint2 st; st.x = packh(a0, a1); st.y = packh(a2, a3);
  *(uint2*)(ab + oo + lo8) = st;
  if (lane < 32){
    int cI = 256 + 2 * lane;
    a4 += w0f * se[0 * DP + cI]     + w1f * se[1 * DP + cI]     + w2f * se[2 * DP + cI]     + se[3 * DP + cI];
    a5 += w0f * se[0 * DP + cI + 1] + w1f * se[1 * DP + cI + 1] + w2f * se[2 * DP + cI + 1] + se[3 * DP + cI + 1];
    *(unsigned*)(ab + oo + lo4) = packh(a4, a5);
  }
}

// ---------------- fused MLP (m97-style staged): h2 = relu(agg@W1+b1)@W2 + b2, + BN stats ----------------
// Block = 32 rows. hid (32x320 fp16, XOR-swizzled) lives in LDS only, built in two
// 320-col halves; phase B accumulates over both halves. All global->LDS staging via
// global_load_lds (width 16), wave-uniform bases, vmcnt(0)+barrier per K-step (m97 recipe).
// Round-5/6 lesson: direct global->VGPR fragment loads serialize (compiler won't pipeline);
// LDS-staged fragments are the proven-schedulable path.
__global__ __launch_bounds__(512) void k_mlp(const u16* __restrict__ agg,
    const u16* __restrict__ W1t, const u16* __restrict__ W2t,
    const float* __restrict__ b1, const float* __restrict__ b2,
    float* __restrict__ h2, float* __restrict__ sums){
  __shared__ __attribute__((aligned(16))) u16 hid[MT * 320];   // 20 KB
  __shared__ __attribute__((aligned(16))) u16 stA[MT * 32];    // 2 KB
  __shared__ __attribute__((aligned(16))) u16 stB[320 * 32];   // 20 KB
  const int tid = threadIdx.x;
  const int lane = tid & 63, w = tid >> 6;
  const int mh = w >> 2, nq = w & 3;          // wave grid 2 x 4
  const int r0 = blockIdx.x * MT;
  const int l15 = lane & 15;
  const unsigned kb16 = ((unsigned)(lane >> 4)) * 16u;
  f32x4 accB[5] = {};
  for (int h = 0; h < 2; ++h){
    f32x4 accA[5] = {};
    // ---- phase A: hid(:, h-half) = relu(agg[32x320] @ W1t[h*320..][320 k]) ----
    for (int ks = 0; ks < 10; ++ks){
      __syncthreads();
      // 1408 chunks: stA = 128 (agg 32 rows x 4 k-chunks), stB = 1280 (W1 320 n-rows x 4)
      #pragma unroll
      for (int i = 0; i < 3; ++i){
        const int cbase = i * 512 + w * 64;          // wave-uniform
        if (cbase < 128){
          const int c = cbase + lane;
          gl_lds16(agg + (size_t)(r0 + (c >> 2)) * DP + ks * 32 + (c & 3) * 8,
                   stA + cbase * 8);
        } else if (cbase < 1408){
          const int c = cbase - 128 + lane;
          gl_lds16(W1t + (size_t)(h * 320 + (c >> 2)) * DP + ks * 32 + (c & 3) * 8,
                   stB + (cbase - 128) * 8);
        }
      }
      asm volatile("s_waitcnt vmcnt(0)" ::: "memory");
      __syncthreads();
      u16x8 af = *(const u16x8*)&stA[(mh * 16 + l15) * 32 + (lane >> 4) * 8];
      u16x8 bf[5];
      #pragma unroll
      for (int n = 0; n < 5; ++n)
        bf[n] = *(const u16x8*)&stB[(nq * 80 + n * 16 + l15) * 32 + (lane >> 4) * 8];
      #pragma unroll
      for (int n = 0; n < 5; ++n) accA[n] = mfma_f16(af, bf[n], accA[n]);
    }
    // epilogue A: relu+b1 -> hid (swizzled). stB reuse is fenced by next loop's barrier.
    #pragma unroll
    for (int n = 0; n < 5; ++n){
      const int colL = nq * 80 + n * 16 + l15;       // 0..319
      const int colG = h * 320 + colL;
      const float bv = (colG < 600) ? b1[colG] : 0.f;
      #pragma unroll
      for (int r = 0; r < 4; ++r){
        const unsigned row = (unsigned)(mh * 16) + ((unsigned)(lane >> 4)) * 4u + (unsigned)r;
        const float vv = fmaxf(accA[n][r] + bv, 0.f);
        const unsigned byte = row * 640u + ((2u * (unsigned)colL) ^ ((row & 7u) << 4));
        *(u16*)((char*)hid + byte) = f2h(vv);
      }
    }
    // ---- phase B: accB += hid_half[32x320] @ W2t[:, h-half k's] ----
    for (int ks = 0; ks < 10; ++ks){
      __syncthreads();   // also fences hid ds_writes (lgkmcnt(0) + barrier)
      #pragma unroll
      for (int i = 0; i < 3; ++i){
        const int cbase = i * 512 + w * 64;
        if (cbase < 1280){
          const int c = cbase + lane;
          gl_lds16(W2t + (size_t)(c >> 2) * HP + (h * 10 + ks) * 32 + (c & 3) * 8,
                   stB + cbase * 8);
        }
      }
      asm volatile("s_waitcnt vmcnt(0)" ::: "memory");
      __syncthreads();
      const unsigned arow = (unsigned)(mh * 16 + l15);
      const unsigned abyte = arow * 640u + (((unsigned)ks * 64u + kb16) ^ ((arow & 7u) << 4));
      u16x8 af = *(const u16x8*)((const char*)hid + abyte);
      u16x8 bf[5];
      #pragma unroll
      for (int n = 0; n < 5; ++n)
        bf[n] = *(const u16x8*)&stB[(nq * 80 + n * 16 + l15) * 32 + (lane >> 4) * 8];
      #pragma unroll
      for (int n = 0; n < 5; ++n) accB[n] = mfma_f16(af, bf[n], accB[n]);
    }
  }
  // epilogue B: b2, fp32 h2 write, fused BN stats
  float sn[5] = {0,0,0,0,0}, qn[5] = {0,0,0,0,0};
  const int row0 = r0 + mh * 16 + (lane >> 4) * 4;
  #pragma unroll
  for (int n = 0; n < 5; ++n){
    const int col = nq * 80 + n * 16 + l15;
    if (col >= D) continue;
    const float bv = b2[col];
    #pragma unroll
    for (int r = 0; r < 4; ++r){
      const int row = row0 + r;
      if (row < NN){
        const float vv = accB[n][r] + bv;
        h2[(size_t)row * D + col] = vv;
        sn[n] += vv; qn[n] += vv * vv;
      }
    }
  }
  #pragma unroll
  for (int n = 0; n < 5; ++n){
    const int col = nq * 80 + n * 16 + l15;
    float s = sn[n], q = qn[n];
    s += __shfl_xor(s, 16); q += __shfl_xor(q, 16);
    s += __shfl_xor(s, 32); q += __shfl_xor(q, 32);
    if (col < D && (lane >> 4) == 0){
      atomicAdd(&sums[col], s);
      atomicAdd(&sums[DP + col], q);
    }
  }
}

// ---------------- BatchNorm apply ----------------
template<bool LAST>
__global__ void k_bnapply(const float* h2, const float* __restrict__ sums,
    const float* __restrict__ gamma, const float* __restrict__ beta,
    u16* __restrict__ hb, float* outp){
  int r = blockIdx.x, c = threadIdx.x;   // block = DP
  float y = 0.f;
  if (c < D){
    float mu  = sums[c] * (1.f / NN);
    float var = sums[DP + c] * (1.f / NN) - mu * mu;
    float x = h2[(size_t)r * D + c];
    float s = var + 1e-5f;
    float inv = rsqrtf(s);
    inv = inv * (1.5f - 0.5f * s * inv * inv);   // Newton: full fp32 accuracy
    y = (x - mu) * inv * gamma[c] + beta[c];
    if (!LAST) y = fmaxf(y, 0.f);
  }
  if (LAST){ if (c < D) outp[(size_t)r * D + c] = y; }
  else hb[(size_t)r * DP + c] = f2h(y);    // pad cols -> 0
}

extern "C" void kernel_launch(void* const* d_in, const int* in_sizes, int n_in,
                              void* d_out, int out_size, void* d_ws, size_t ws_size,
                              hipStream_t stream){
  (void)in_sizes; (void)n_in; (void)out_size; (void)ws_size;
  const int*   x    = (const int*)d_in[0];
  const int*   ei   = (const int*)d_in[1];
  const int*   ea   = (const int*)d_in[2];
  const float* xemb = (const float*)d_in[3];
  const float* eemb = (const float*)d_in[4];
  const float* W1   = (const float*)d_in[5];
  const float* b1   = (const float*)d_in[6];
  const float* W2   = (const float*)d_in[7];
  const float* b2   = (const float*)d_in[8];
  const float* gam  = (const float*)d_in[9];
  const float* bet  = (const float*)d_in[10];
  float* out = (float*)d_out;

  char* w = (char*)d_ws;
  size_t off = 0;
  auto alloc = [&](size_t b){ void* p = w + off; off += (b + 255) & ~(size_t)255; return p; };
  u16* hb    = (u16*)alloc((size_t)NROWPAD * DP * 2);   // 32 MB
  u16* aggb  = (u16*)alloc((size_t)NROWPAD * DP * 2);   // 32 MB
  u16* W1t   = (u16*)alloc((size_t)5 * HP * DP * 2);    // 2 MB
  u16* W2t   = (u16*)alloc((size_t)5 * DP * HP * 2);    // 2 MB
  int* rp    = (int*)alloc((NN + 1) * 4);
  int* cnt   = (int*)alloc((size_t)NN * 4);
  int* cur   = (int*)alloc((size_t)NN * 4);
  int* bsum  = (int*)alloc(64 * 4);
  int* pack  = (int*)alloc((size_t)NE * 4);
  int* ccnt  = (int*)alloc((size_t)NN * 12 * 4);        // 2.4 MB
  float* sums5 = (float*)alloc(5 * 2 * DP * 4);         // per-layer BN stat buffers
  float* h2  = out;   // reuse d_out as [NN][300] fp32 activation buffer

  hipMemsetAsync(cnt, 0, NN * 4, stream);
  hipMemsetAsync(ccnt, 0, (size_t)NN * 12 * 4, stream);
  hipMemsetAsync(sums5, 0, 5 * 2 * DP * 4, stream);
  k_count<<<NE / 256, 256, 0, stream>>>(ei, ea, cnt, ccnt);
  k_scan1<<<(NN + 1023) / 1024, 1024, 0, stream>>>(cnt, rp, bsum);
  k_scan2<<<1, 64, 0, stream>>>(bsum, (NN + 1023) / 1024);
  k_scan3<<<(NN + 255) / 256, 256, 0, stream>>>(rp, cur, bsum);
  k_fill<<<NE / 256, 256, 0, stream>>>(ei, cur, pack);
  k_wconv<<<(5 * HP * DP) / 256, 256, 0, stream>>>(W1, W2, W1t, W2t);
  k_nodeemb<<<NN, DP, 0, stream>>>(x, xemb, hb);

  for (int l = 0; l < 5; ++l){
    float* sums = sums5 + l * 2 * DP;
    k_agg<<<(NN + 3) / 4, 256, 0, stream>>>(hb, rp, pack, ccnt, eemb + (size_t)l * 6 * D, aggb);
    k_mlp<<<NROWPAD / MT, 512, 0, stream>>>(aggb,
        W1t + (size_t)l * HP * DP, W2t + (size_t)l * DP * HP,
        b1 + l * 600, b2 + l * D, h2, sums);
    if (l < 4) k_bnapply<false><<<NN, DP, 0, stream>>>(h2, sums, gam + l * D, bet + l * D, hb, nullptr);
    else       k_bnapply<true ><<<NN, DP, 0, stream>>>(h2, sums, gam + l * D, bet + l * D, nullptr, out);
  }
}